// Round 5
// baseline (889.923 us; speedup 1.0000x reference)
//
#include <hip/hip_runtime.h>
#include <math.h>

// Problem constants
#define HW   16384   // 128*128
#define IMW  128
#define IMH  128
#define CC   384
#define CC2  768
#define NH   8
#define DH   48

typedef unsigned short u16;
typedef __attribute__((ext_vector_type(8))) short short8;
typedef __attribute__((ext_vector_type(16))) float f32x16;

// async global->LDS, 16B per lane. dst is wave-uniform base; HW adds lane*16.
__device__ __forceinline__ void gld16(const u16* g, u16* l) {
    __builtin_amdgcn_global_load_lds(
        (const __attribute__((address_space(1))) unsigned int*)(uintptr_t)g,
        (__attribute__((address_space(3))) unsigned int*)(uintptr_t)l, 16, 0, 0);
}

__device__ __forceinline__ void bf16split(float x, unsigned& hb16, unsigned& lb16) {
    const unsigned u = __float_as_uint(x);
    const unsigned hb = (u + 0x7FFFu + ((u >> 16) & 1u)) & 0xFFFF0000u;
    const float lo = x - __uint_as_float(hb);
    const unsigned v = __float_as_uint(lo);
    hb16 = hb >> 16;
    lb16 = ((v + 0x7FFFu + ((v >> 16) & 1u)) >> 16) & 0xFFFFu;
}

// ---------------------------------------------------------------------------
// Split all 5 pointwise-conv weight tensors into bf16 hi/lo (concatenated).
// ---------------------------------------------------------------------------
__global__ void wsplit_k(const float* __restrict__ w0, const float* __restrict__ w1,
                         const float* __restrict__ w2, const float* __restrict__ w3,
                         const float* __restrict__ w4,
                         u16* __restrict__ Wh, u16* __restrict__ Wl)
{
    const int i = blockIdx.x * 256 + threadIdx.x;
    if (i >= 1032192) return;
    float x;
    if (i < 147456)      x = w0[i];
    else if (i < 294912) x = w1[i - 147456];
    else if (i < 589824) x = w2[i - 294912];
    else if (i < 884736) x = w3[i - 589824];
    else                 x = w4[i - 884736];
    unsigned h, l;
    bf16split(x, h, l);
    Wh[i] = (u16)h;
    Wl[i] = (u16)l;
}

// ---------------------------------------------------------------------------
// Transpose + split: X fp32 [C][HW] -> XTh, XTl bf16 [HW][C] (plain layout,
// no swizzle: GEMM LDS layout is now conflict-free by construction).
// ---------------------------------------------------------------------------
__global__ __launch_bounds__(256)
void trsplit_k(const float* __restrict__ X, u16* __restrict__ XTh,
               u16* __restrict__ XTl, int C)
{
    __shared__ float tl[64][65];
    const int t  = threadIdx.x;
    const int n0 = blockIdx.x * 64;
    const int k0 = blockIdx.y * 64;
    #pragma unroll
    for (int p = 0; p < 4; ++p) {
        const int kk = p * 16 + (t >> 4);
        const int nn = (t & 15) * 4;
        *(float4*)&tl[kk][nn] = *(const float4*)(X + (size_t)(k0 + kk) * HW + n0 + nn);
    }
    __syncthreads();
    const int n    = t >> 2;          // 0..63
    const int kseg = (t & 3) * 16;    // 0,16,32,48
    const int gn   = n0 + n;
    #pragma unroll
    for (int h = 0; h < 2; ++h) {
        unsigned hw_[4], lw_[4];
        #pragma unroll
        for (int i2 = 0; i2 < 4; ++i2) {
            unsigned hp = 0, lp = 0;
            #pragma unroll
            for (int e = 0; e < 2; ++e) {
                unsigned hb, lb;
                bf16split(tl[kseg + h * 8 + i2 * 2 + e][n], hb, lb);
                hp |= hb << (16 * e);
                lp |= lb << (16 * e);
            }
            hw_[i2] = hp; lw_[i2] = lp;
        }
        const int kb = k0 + kseg + h * 8;
        const size_t off = (size_t)gn * C + kb;
        *(uint4*)(XTh + off) = make_uint4(hw_[0], hw_[1], hw_[2], hw_[3]);
        *(uint4*)(XTl + off) = make_uint4(lw_[0], lw_[1], lw_[2], lw_[3]);
    }
}

// ---------------------------------------------------------------------------
// Split-bf16 MFMA GEMM, double-buffered 2-phase pipeline.
// Out[m,n] = sum_k W[m,k] X[k,n], 3-term hi/lo split.
// Tile 128x128, BK=32, 4 waves of 64x64, mfma 32x32x16.
// LDS layout [ks][hi32][oct][lo32][8]: each per-wave fragment ds_read_b128 is
// a contiguous 1024B block (lane l reads base + l*16B) -> conflict-free.
// GATE=1: epilogue qin = g*q1+(1-g)*q2, g=sigmoid(acc).
// ---------------------------------------------------------------------------
template<int GATE>
__global__ __launch_bounds__(256, 2)
void gemm_mfma_k(const u16* __restrict__ Wh, const u16* __restrict__ Wl,
                 const u16* __restrict__ XTh, const u16* __restrict__ XTl,
                 int K, float* __restrict__ Out,
                 const float* __restrict__ q1p, const float* __restrict__ q2p)
{
    __shared__ u16 Ah[2][4096], Al[2][4096], Bh[2][4096], Bl[2][4096];
    const int t = threadIdx.x;
    const int w = t >> 6;
    const int l = t & 63;
    const int l31 = l & 31, lh = l >> 5;
    const int nBase = blockIdx.x * 128;
    const int mBase = blockIdx.y * 128;
    const int wmh = (w >> 1) * 2;   // wave's A hi32 base (0 or 2)
    const int wnh = (w & 1) * 2;    // wave's B hi32 base (0 or 2)

    // staging: 8 chunks of 512 u16; wave w owns jj = 2w, 2w+1.
    // chunk jj = (ks = jj>>2, hi = jj&3); lane l = (oct = l>>5, lo = l&31)
    const int jj0 = w * 2, jj1 = jj0 + 1;
    const int offA0 = (mBase + (jj0 & 3) * 32 + l31) * K + (jj0 >> 2) * 16 + lh * 8;
    const int offA1 = (mBase + (jj1 & 3) * 32 + l31) * K + (jj1 >> 2) * 16 + lh * 8;
    const int offB0 = (nBase + (jj0 & 3) * 32 + l31) * K + (jj0 >> 2) * 16 + lh * 8;
    const int offB1 = (nBase + (jj1 & 3) * 32 + l31) * K + (jj1 >> 2) * 16 + lh * 8;
    const int ldst0 = jj0 * 512, ldst1 = jj1 * 512;

#define STAGE(buf, k0)                                  \
    do {                                                \
        gld16(Wh  + offA0 + (k0), Ah[buf] + ldst0);     \
        gld16(Wh  + offA1 + (k0), Ah[buf] + ldst1);     \
        gld16(Wl  + offA0 + (k0), Al[buf] + ldst0);     \
        gld16(Wl  + offA1 + (k0), Al[buf] + ldst1);     \
        gld16(XTh + offB0 + (k0), Bh[buf] + ldst0);     \
        gld16(XTh + offB1 + (k0), Bh[buf] + ldst1);     \
        gld16(XTl + offB0 + (k0), Bl[buf] + ldst0);     \
        gld16(XTl + offB1 + (k0), Bl[buf] + ldst1);     \
    } while (0)

    f32x16 acc[2][2];
    #pragma unroll
    for (int i = 0; i < 2; ++i)
        #pragma unroll
        for (int j = 0; j < 2; ++j)
            #pragma unroll
            for (int r = 0; r < 16; ++r) acc[i][j][r] = 0.f;

    const int NC = K >> 5;
    STAGE(0, 0);
    __syncthreads();
    int p = 0;
    for (int c = 0; c < NC; ++c) {
        if (c + 1 < NC) STAGE(p ^ 1, (c + 1) * 32);   // prefetch next chunk

        short8 ah[2][2], al[2][2], bh[2][2], bl[2][2];
        #pragma unroll
        for (int ks = 0; ks < 2; ++ks)
            #pragma unroll
            for (int fm = 0; fm < 2; ++fm) {
                const int ia = (ks * 4 + wmh + fm) * 512 + l * 8;
                ah[fm][ks] = *(const short8*)(&Ah[p][ia]);
                al[fm][ks] = *(const short8*)(&Al[p][ia]);
            }
        #pragma unroll
        for (int ks = 0; ks < 2; ++ks)
            #pragma unroll
            for (int fn = 0; fn < 2; ++fn) {
                const int ib = (ks * 4 + wnh + fn) * 512 + l * 8;
                bh[fn][ks] = *(const short8*)(&Bh[p][ib]);
                bl[fn][ks] = *(const short8*)(&Bl[p][ib]);
            }
        #pragma unroll
        for (int ks = 0; ks < 2; ++ks)
            #pragma unroll
            for (int fm = 0; fm < 2; ++fm)
                #pragma unroll
                for (int fn = 0; fn < 2; ++fn) {
                    acc[fm][fn] = __builtin_amdgcn_mfma_f32_32x32x16_bf16(ah[fm][ks], bh[fn][ks], acc[fm][fn], 0, 0, 0);
                    acc[fm][fn] = __builtin_amdgcn_mfma_f32_32x32x16_bf16(ah[fm][ks], bl[fn][ks], acc[fm][fn], 0, 0, 0);
                    acc[fm][fn] = __builtin_amdgcn_mfma_f32_32x32x16_bf16(al[fm][ks], bh[fn][ks], acc[fm][fn], 0, 0, 0);
                }
        __syncthreads();   // drains prefetch (vmcnt0) + protects buffer reuse
        p ^= 1;
    }
#undef STAGE

    // epilogue: D col = lane&31, row = (r&3) + 8*(r>>2) + 4*(lane>>5)
    #pragma unroll
    for (int fm = 0; fm < 2; ++fm)
        #pragma unroll
        for (int fn = 0; fn < 2; ++fn) {
            const int mb = mBase + (wmh + fm) * 32 + lh * 4;
            const int nb = nBase + (wnh + fn) * 32 + l31;
            #pragma unroll
            for (int r = 0; r < 16; ++r) {
                const int m = mb + (r & 3) + 8 * (r >> 2);
                float v = acc[fm][fn][r];
                const size_t off = (size_t)m * HW + nb;
                if (GATE) {
                    const float g = 1.f / (1.f + expf(-v));
                    v = g * q1p[off] + (1.f - g) * q2p[off];
                }
                Out[off] = v;
            }
        }
}

// ---------------------------------------------------------------------------
// Depthwise 3x3, SAME (zero) padding. Per-batch: in/out are [Cg, HW].
// ---------------------------------------------------------------------------
__global__ __launch_bounds__(256)
void dw3x3_k(const float* __restrict__ in, const float* __restrict__ w9,
             float* __restrict__ out)
{
    const int c  = blockIdx.y;
    const int y0 = blockIdx.x * 8;
    __shared__ float tile[10][IMW];

    const float* inc = in + (size_t)c * HW;
    for (int i = threadIdx.x; i < 10 * IMW; i += 256) {
        const int ry = i >> 7, rx = i & 127;
        const int gy = y0 + ry - 1;
        tile[ry][rx] = ((unsigned)gy < (unsigned)IMH) ? inc[gy * IMW + rx] : 0.f;
    }
    float w[9];
    #pragma unroll
    for (int i = 0; i < 9; ++i) w[i] = w9[c * 9 + i];
    __syncthreads();

    const int x  = threadIdx.x & 127;
    const int r0 = threadIdx.x >> 7;
    #pragma unroll
    for (int kk = 0; kk < 4; ++kk) {
        const int ry = r0 * 4 + kk;
        float s = 0.f;
        #pragma unroll
        for (int dy = 0; dy < 3; ++dy) {
            #pragma unroll
            for (int dx = 0; dx < 3; ++dx) {
                const int xx = x + dx - 1;
                const float v = ((unsigned)xx < (unsigned)IMW) ? tile[ry + dy][xx] : 0.f;
                s += w[dy * 3 + dx] * v;
            }
        }
        out[(size_t)c * HW + (y0 + ry) * IMW + x] = s;
    }
}

// ---------------------------------------------------------------------------
// Gram + sum-of-squares (unchanged, validated).
// ---------------------------------------------------------------------------
__global__ __launch_bounds__(256)
void gram_k(const float* __restrict__ q, const float* __restrict__ k,
            float* __restrict__ S, float* __restrict__ ssq, float* __restrict__ ssk)
{
    const int h = blockIdx.y;
    __shared__ float qs[48][65];
    __shared__ float ks[48][65];
    const int t   = threadIdx.x;
    const int tdd = t & 15;
    const int tcc = t >> 4;

    float acc[3][3];
    #pragma unroll
    for (int i = 0; i < 3; ++i)
        #pragma unroll
        for (int j = 0; j < 3; ++j) acc[i][j] = 0.f;
    float sq = 0.f, sk = 0.f;

    for (int ch = 0; ch < 8; ++ch) {
        const int n0 = (blockIdx.x + ch * 32) * 64;
        __syncthreads();
        for (int i = t; i < 48 * 16; i += 256) {
            const int cc = i >> 4, f4 = (i & 15) * 4;
            const float4 qv = *(const float4*)(q + (size_t)(h * 48 + cc) * HW + n0 + f4);
            const float4 kv = *(const float4*)(k + (size_t)(h * 48 + cc) * HW + n0 + f4);
            qs[cc][f4 + 0] = qv.x; qs[cc][f4 + 1] = qv.y; qs[cc][f4 + 2] = qv.z; qs[cc][f4 + 3] = qv.w;
            ks[cc][f4 + 0] = kv.x; ks[cc][f4 + 1] = kv.y; ks[cc][f4 + 2] = kv.z; ks[cc][f4 + 3] = kv.w;
        }
        __syncthreads();
        #pragma unroll 4
        for (int n = 0; n < 64; ++n) {
            float qv[3], kv[3];
            #pragma unroll
            for (int j = 0; j < 3; ++j) { qv[j] = qs[tcc + 16 * j][n]; kv[j] = ks[tdd + 16 * j][n]; }
            #pragma unroll
            for (int i = 0; i < 3; ++i)
                #pragma unroll
                for (int j = 0; j < 3; ++j)
                    acc[i][j] += qv[i] * kv[j];
        }
        if (t < 48) {
            float s = 0.f;
            #pragma unroll 8
            for (int n = 0; n < 64; ++n) s += qs[t][n] * qs[t][n];
            sq += s;
        } else if (t >= 128 && t < 176) {
            const int cc = t - 128;
            float s = 0.f;
            #pragma unroll 8
            for (int n = 0; n < 64; ++n) s += ks[cc][n] * ks[cc][n];
            sk += s;
        }
    }
    #pragma unroll
    for (int i = 0; i < 3; ++i)
        #pragma unroll
        for (int j = 0; j < 3; ++j)
            atomicAdd(&S[(size_t)(h * 48 + tcc + 16 * i) * 48 + tdd + 16 * j], acc[i][j]);
    if (t < 48)                   atomicAdd(&ssq[h * 48 + t], sq);
    else if (t >= 128 && t < 176) atomicAdd(&ssk[h * 48 + t - 128], sk);
}

// ---------------------------------------------------------------------------
// Scale + softmax (unchanged).
// ---------------------------------------------------------------------------
__global__ void softmax_k(float* __restrict__ S, const float* __restrict__ ssq,
                          const float* __restrict__ ssk, const float* __restrict__ temp)
{
    const int h  = blockIdx.x;
    const int cc = threadIdx.x;
    if (cc >= 48) return;
    const float rq = 1.f / fmaxf(sqrtf(ssq[h * 48 + cc]), 1e-12f);
    const float T  = temp[h];
    float l[48];
    float mx = -1e30f;
    #pragma unroll
    for (int d = 0; d < 48; ++d) {
        const float rk = 1.f / fmaxf(sqrtf(ssk[h * 48 + d]), 1e-12f);
        const float v  = S[(size_t)(h * 48 + cc) * 48 + d] * rq * rk * T;
        l[d] = v;
        mx = fmaxf(mx, v);
    }
    float sum = 0.f;
    #pragma unroll
    for (int d = 0; d < 48; ++d) { const float e = expf(l[d] - mx); l[d] = e; sum += e; }
    const float inv = 1.f / sum;
    #pragma unroll
    for (int d = 0; d < 48; ++d) S[(size_t)(h * 48 + cc) * 48 + d] = l[d] * inv;
}

// ---------------------------------------------------------------------------
// out[h*48+c, n] = sum_d A[h,c,d] * v[h*48+d, n] (unchanged).
// ---------------------------------------------------------------------------
__global__ __launch_bounds__(256)
void attnv_k(const float* __restrict__ A, const float* __restrict__ v,
             float* __restrict__ out)
{
    const int h  = blockIdx.y;
    const int n0 = blockIdx.x * 64;
    __shared__ float As[48][48];
    __shared__ float Vs[48][64];
    const int t = threadIdx.x;

    for (int i = t; i < 48 * 12; i += 256) {
        const int cc = i / 12, d4 = (i % 12) * 4;
        *(float4*)&As[cc][d4] = *(const float4*)(A + (size_t)(h * 48 + cc) * 48 + d4);
    }
    for (int i = t; i < 48 * 16; i += 256) {
        const int dd = i >> 4, f4 = (i & 15) * 4;
        *(float4*)&Vs[dd][f4] = *(const float4*)(v + (size_t)(h * 48 + dd) * HW + n0 + f4);
    }
    __syncthreads();

    const int n4 = (t & 15) * 4;
    const int cg = t >> 4;
    float o[3][4];
    #pragma unroll
    for (int i = 0; i < 3; ++i)
        #pragma unroll
        for (int j = 0; j < 4; ++j) o[i][j] = 0.f;

    #pragma unroll
    for (int d0 = 0; d0 < 48; d0 += 8) {
        float vr[8][4];
        #pragma unroll
        for (int di = 0; di < 8; ++di) {
            const float4 x = *(const float4*)&Vs[d0 + di][n4];
            vr[di][0] = x.x; vr[di][1] = x.y; vr[di][2] = x.z; vr[di][3] = x.w;
        }
        #pragma unroll
        for (int ci = 0; ci < 3; ++ci) {
            const int cc = cg * 3 + ci;
            const float4 a0 = *(const float4*)&As[cc][d0];
            const float4 a1 = *(const float4*)&As[cc][d0 + 4];
            const float a[8] = {a0.x, a0.y, a0.z, a0.w, a1.x, a1.y, a1.z, a1.w};
            #pragma unroll
            for (int di = 0; di < 8; ++di)
                #pragma unroll
                for (int j = 0; j < 4; ++j)
                    o[ci][j] += a[di] * vr[di][j];
        }
    }
    #pragma unroll
    for (int ci = 0; ci < 3; ++ci) {
        const int cc = cg * 3 + ci;
        *(float4*)(out + (size_t)(h * 48 + cc) * HW + n0 + n4) =
            make_float4(o[ci][0], o[ci][1], o[ci][2], o[ci][3]);
    }
}

// ---------------------------------------------------------------------------
extern "C" void kernel_launch(void* const* d_in, const int* in_sizes, int n_in,
                              void* d_out, int out_size, void* d_ws, size_t ws_size,
                              hipStream_t stream)
{
    const float* prompt    = (const float*)d_in[0];
    const float* xmod      = (const float*)d_in[1];
    const float* yin       = (const float*)d_in[2];
    const float* q1_w      = (const float*)d_in[3];
    const float* q2_w      = (const float*)d_in[4];
    const float* q_dw_w    = (const float*)d_in[5];
    const float* gate_dw_w = (const float*)d_in[6];
    const float* gate_pw_w = (const float*)d_in[7];
    const float* kv_w      = (const float*)d_in[8];
    const float* kv_dw_w   = (const float*)d_in[9];
    const float* proj_w    = (const float*)d_in[10];
    const float* temp      = (const float*)d_in[11];
    float* out = (float*)d_out;
    float* ws  = (float*)d_ws;

    const size_t BUF  = (size_t)CC2 * HW;          // 12.58M floats
    const size_t HALF = (size_t)CC * HW;
    float* q12 = ws;                               // [768,HW]: q1|q2 -> qin|q
    float* t1  = ws + BUF;                         // [768,HW]: dcat -> k|v  (+XT384 alias)
    float* t2  = ws + 2 * BUF;                     // [768,HW]: XT768 -> kvp -> attn_out
    u16*   Wh  = (u16*)(ws + 3 * BUF);             // 1032192 u16
    u16*   Wl  = Wh + 1032192;
    float* S   = ws + 3 * BUF + 1032192;           // [8,48,48]
    float* ssq = S + NH * DH * DH;
    float* ssk = ssq + CC;

    // weight offsets in Wh/Wl (u16 elems)
    const int WO_Q1 = 0, WO_Q2 = 147456, WO_GATE = 294912, WO_KV = 589824, WO_PROJ = 884736;

    // XT aliases
    u16* XT2h = (u16*)t2;                // K=768 capacity
    u16* XT2l = XT2h + (size_t)HW * CC2;
    u16* XT1h = (u16*)t1;                // K=384 capacity
    u16* XT1l = XT1h + (size_t)HW * CC;

    const dim3 blk(256);

    // one-time weight split
    wsplit_k<<<dim3(4032), blk, 0, stream>>>(q1_w, q2_w, gate_pw_w, kv_w, proj_w, Wh, Wl);

    for (int b = 0; b < 2; ++b) {
        const size_t ib = (size_t)b * CC * HW;

        // q1 = q1_w * prompt -> q12[0:384]
        trsplit_k<<<dim3(256, 6), blk, 0, stream>>>(prompt + ib, XT1h, XT1l, CC);
        gemm_mfma_k<0><<<dim3(128, 3), blk, 0, stream>>>(Wh + WO_Q1, Wl + WO_Q1, XT1h, XT1l, CC, q12, nullptr, nullptr);
        // q2 = q2_w * x_mod -> q12[384:768]
        trsplit_k<<<dim3(256, 6), blk, 0, stream>>>(xmod + ib, XT1h, XT1l, CC);
        gemm_mfma_k<0><<<dim3(128, 3), blk, 0, stream>>>(Wh + WO_Q2, Wl + WO_Q2, XT1h, XT1l, CC, q12 + HALF, nullptr, nullptr);
        // dcat = dw3x3(q12, gate_dw_w) -> t1 (768 ch)
        dw3x3_k<<<dim3(16, CC2), blk, 0, stream>>>(q12, gate_dw_w, t1);
        // gate pw + sigmoid + blend -> q12[0:384] (in place over q1)
        trsplit_k<<<dim3(256, 12), blk, 0, stream>>>(t1, XT2h, XT2l, CC2);
        gemm_mfma_k<1><<<dim3(128, 3), blk, 0, stream>>>(Wh + WO_GATE, Wl + WO_GATE, XT2h, XT2l, CC2, q12, q12, q12 + HALF);
        // q = dw3x3(qin, q_dw_w) -> q12[384:768]
        dw3x3_k<<<dim3(16, CC), blk, 0, stream>>>(q12, q_dw_w, q12 + HALF);
        // kvp = kv_w * y -> t2
        trsplit_k<<<dim3(256, 6), blk, 0, stream>>>(yin + ib, XT1h, XT1l, CC);
        gemm_mfma_k<0><<<dim3(128, 6), blk, 0, stream>>>(Wh + WO_KV, Wl + WO_KV, XT1h, XT1l, CC, t2, nullptr, nullptr);
        // kv = dw3x3(t2, kv_dw_w) -> t1 : k|v
        dw3x3_k<<<dim3(16, CC2), blk, 0, stream>>>(t2, kv_dw_w, t1);
        // Gram + sumsq
        hipMemsetAsync(S, 0, (NH * DH * DH + 2 * CC) * sizeof(float), stream);
        gram_k<<<dim3(32, NH), blk, 0, stream>>>(q12 + HALF, t1, S, ssq, ssk);
        softmax_k<<<dim3(NH), dim3(64), 0, stream>>>(S, ssq, ssk, temp);
        // attn_out = A * v -> t2[0:384]
        attnv_k<<<dim3(HW / 64, NH), blk, 0, stream>>>(S, t1 + HALF, t2);
        // final projection -> out
        trsplit_k<<<dim3(256, 6), blk, 0, stream>>>(t2, XT1h, XT1l, CC);
        gemm_mfma_k<0><<<dim3(128, 3), blk, 0, stream>>>(Wh + WO_PROJ, Wl + WO_PROJ, XT1h, XT1l, CC, out + ib, nullptr, nullptr);
    }
}

// Round 6
// 792.954 us; speedup vs baseline: 1.1223x; 1.1223x over previous
//
#include <hip/hip_runtime.h>
#include <math.h>

// Problem constants
#define HW   16384   // 128*128
#define IMW  128
#define IMH  128
#define CC   384
#define CC2  768
#define NH   8
#define DH   48

typedef unsigned short u16;
typedef __attribute__((ext_vector_type(8))) short short8;
typedef __attribute__((ext_vector_type(16))) float f32x16;

// async global->LDS, 16B per lane. dst is wave-uniform base; HW adds lane*16.
__device__ __forceinline__ void gld16(const u16* g, u16* l) {
    __builtin_amdgcn_global_load_lds(
        (const __attribute__((address_space(1))) unsigned int*)(uintptr_t)g,
        (__attribute__((address_space(3))) unsigned int*)(uintptr_t)l, 16, 0, 0);
}

__device__ __forceinline__ void bf16split(float x, unsigned& hb16, unsigned& lb16) {
    const unsigned u = __float_as_uint(x);
    const unsigned hb = (u + 0x7FFFu + ((u >> 16) & 1u)) & 0xFFFF0000u;
    const float lo = x - __uint_as_float(hb);
    const unsigned v = __float_as_uint(lo);
    hb16 = hb >> 16;
    lb16 = ((v + 0x7FFFu + ((v >> 16) & 1u)) >> 16) & 0xFFFFu;
}

// Packed-tile address for element (row r of 128-tile, k): tiles of 128x32.
// layout: [tile][kchunk][jj=ks*4+(r>>5)][oct=(k>>3)&1][lo=r&31][k&7]
// -> every GEMM staging gld16 reads 1024 CONTIGUOUS bytes.

// ---------------------------------------------------------------------------
// Pack+split all 5 pointwise weights into MFMA-native tiled bf16 hi/lo.
// One thread = one 8-k octet of one matrix.
// ---------------------------------------------------------------------------
__global__ void wsplit_k(const float* __restrict__ w0, const float* __restrict__ w1,
                         const float* __restrict__ w2, const float* __restrict__ w3,
                         const float* __restrict__ w4,
                         u16* __restrict__ Wh, u16* __restrict__ Wl)
{
    const int i = blockIdx.x * 256 + threadIdx.x;
    if (i >= 129024) return;
    const float* src; int j, K, wo;
    if (i < 18432)       { src = w0; j = i;          K = 384; wo = 0; }
    else if (i < 36864)  { src = w1; j = i - 18432;  K = 384; wo = 147456; }
    else if (i < 73728)  { src = w2; j = i - 36864;  K = 768; wo = 294912; }
    else if (i < 110592) { src = w3; j = i - 73728;  K = 384; wo = 589824; }
    else                 { src = w4; j = i - 110592; K = 384; wo = 884736; }
    const int kpo = K >> 3;
    const int m  = j / kpo;
    const int k  = (j % kpo) * 8;

    unsigned hp[4], lp[4];
    #pragma unroll
    for (int q = 0; q < 4; ++q) {
        unsigned h0, l0, h1, l1;
        bf16split(src[(size_t)m * K + k + q * 2],     h0, l0);
        bf16split(src[(size_t)m * K + k + q * 2 + 1], h1, l1);
        hp[q] = h0 | (h1 << 16);
        lp[q] = l0 | (l1 << 16);
    }
    const int NC = K >> 5, mtile = m >> 7, ml = m & 127;
    const int c = k >> 5, ks = (k >> 4) & 1, oct = (k >> 3) & 1;
    const int jj = ks * 4 + (ml >> 5), lo = ml & 31;
    const size_t off = (size_t)wo + ((size_t)(mtile * NC + c)) * 4096 + jj * 512 + oct * 256 + lo * 8;
    *(uint4*)(Wh + off) = make_uint4(hp[0], hp[1], hp[2], hp[3]);
    *(uint4*)(Wl + off) = make_uint4(lp[0], lp[1], lp[2], lp[3]);
}

// ---------------------------------------------------------------------------
// Transpose + split + pack: X fp32 [C][HW] -> XTh/XTl bf16 in MFMA-native
// tiled layout over (n in 128-tiles) x (k chunks of 32).
// ---------------------------------------------------------------------------
__global__ __launch_bounds__(256)
void trsplit_k(const float* __restrict__ X, u16* __restrict__ XTh,
               u16* __restrict__ XTl, int C)
{
    __shared__ float tl[64][65];
    const int t  = threadIdx.x;
    const int n0 = blockIdx.x * 64;
    const int k0 = blockIdx.y * 64;
    const int NC = C >> 5;
    #pragma unroll
    for (int p = 0; p < 4; ++p) {
        const int kk = p * 16 + (t >> 4);
        const int nn = (t & 15) * 4;
        *(float4*)&tl[kk][nn] = *(const float4*)(X + (size_t)(k0 + kk) * HW + n0 + nn);
    }
    __syncthreads();
    const int n    = t >> 2;          // 0..63
    const int kseg = (t & 3) * 16;    // 0,16,32,48
    const int gn    = n0 + n;
    const int ntile = gn >> 7, nl = gn & 127;
    const int hi = nl >> 5, lo = nl & 31;
    #pragma unroll
    for (int h = 0; h < 2; ++h) {
        unsigned hw_[4], lw_[4];
        #pragma unroll
        for (int i2 = 0; i2 < 4; ++i2) {
            unsigned hpk = 0, lpk = 0;
            #pragma unroll
            for (int e = 0; e < 2; ++e) {
                unsigned hb, lb;
                bf16split(tl[kseg + h * 8 + i2 * 2 + e][n], hb, lb);
                hpk |= hb << (16 * e);
                lpk |= lb << (16 * e);
            }
            hw_[i2] = hpk; lw_[i2] = lpk;
        }
        const int kb = k0 + kseg + h * 8;
        const int c = kb >> 5, ks = (kb >> 4) & 1, oct = (kb >> 3) & 1;
        const int jj = ks * 4 + hi;
        const size_t off = ((size_t)(ntile * NC + c)) * 4096 + jj * 512 + oct * 256 + lo * 8;
        *(uint4*)(XTh + off) = make_uint4(hw_[0], hw_[1], hw_[2], hw_[3]);
        *(uint4*)(XTl + off) = make_uint4(lw_[0], lw_[1], lw_[2], lw_[3]);
    }
}

// ---------------------------------------------------------------------------
// Split-bf16 MFMA GEMM, double-buffered, packed-tile operands.
// Tile 128x128, BK=32, 4 waves of 64x64, mfma 32x32x16.
// Every gld16 stages 1024 contiguous global bytes; every fragment
// ds_read_b128 is a contiguous 1024B LDS block (0 bank conflicts).
// GATE=1: epilogue qin = g*q1+(1-g)*q2, g=sigmoid(acc).
// ---------------------------------------------------------------------------
template<int GATE>
__global__ __launch_bounds__(256, 2)
void gemm_mfma_k(const u16* __restrict__ Wh, const u16* __restrict__ Wl,
                 const u16* __restrict__ XTh, const u16* __restrict__ XTl,
                 int K, float* __restrict__ Out,
                 const float* __restrict__ q1p, const float* __restrict__ q2p)
{
    __shared__ u16 Ah[2][4096], Al[2][4096], Bh[2][4096], Bl[2][4096];
    const int t = threadIdx.x;
    const int w = t >> 6;
    const int l = t & 63;
    const int l31 = l & 31, lh = l >> 5;

    // bijective XCD-chunked swizzle (all grids are multiples of 8)
    const int gx  = gridDim.x;
    const int nwg = gx * gridDim.y;
    int wg = blockIdx.y * gx + blockIdx.x;
    wg = (wg & 7) * (nwg >> 3) + (wg >> 3);
    const int bx = wg % gx, by = wg / gx;

    const int nBase = bx * 128;
    const int mBase = by * 128;
    const int wmh = (w >> 1) * 2;   // wave's A hi32 base (0 or 2)
    const int wnh = (w & 1) * 2;    // wave's B hi32 base (0 or 2)

    const int NC = K >> 5;
    const int jj0 = w * 2, jj1 = jj0 + 1;
    const int ldst0 = jj0 * 512, ldst1 = jj1 * 512;
    const size_t tA = (size_t)by * NC * 4096 + l * 8;
    const size_t tB = (size_t)bx * NC * 4096 + l * 8;

#define STAGE(buf, c)                                                      \
    do {                                                                   \
        const size_t oA = tA + (size_t)(c) * 4096;                         \
        const size_t oB = tB + (size_t)(c) * 4096;                         \
        gld16(Wh  + oA + ldst0, Ah[buf] + ldst0);                          \
        gld16(Wh  + oA + ldst1, Ah[buf] + ldst1);                          \
        gld16(Wl  + oA + ldst0, Al[buf] + ldst0);                          \
        gld16(Wl  + oA + ldst1, Al[buf] + ldst1);                          \
        gld16(XTh + oB + ldst0, Bh[buf] + ldst0);                          \
        gld16(XTh + oB + ldst1, Bh[buf] + ldst1);                          \
        gld16(XTl + oB + ldst0, Bl[buf] + ldst0);                          \
        gld16(XTl + oB + ldst1, Bl[buf] + ldst1);                          \
    } while (0)

    f32x16 acc[2][2];
    #pragma unroll
    for (int i = 0; i < 2; ++i)
        #pragma unroll
        for (int j = 0; j < 2; ++j)
            #pragma unroll
            for (int r = 0; r < 16; ++r) acc[i][j][r] = 0.f;

    STAGE(0, 0);
    __syncthreads();
    int p = 0;
    for (int c = 0; c < NC; ++c) {
        if (c + 1 < NC) STAGE(p ^ 1, c + 1);   // prefetch next chunk

        short8 ah[2][2], al[2][2], bh[2][2], bl[2][2];
        #pragma unroll
        for (int ks = 0; ks < 2; ++ks)
            #pragma unroll
            for (int fm = 0; fm < 2; ++fm) {
                const int ia = (ks * 4 + wmh + fm) * 512 + l * 8;
                ah[fm][ks] = *(const short8*)(&Ah[p][ia]);
                al[fm][ks] = *(const short8*)(&Al[p][ia]);
            }
        #pragma unroll
        for (int ks = 0; ks < 2; ++ks)
            #pragma unroll
            for (int fn = 0; fn < 2; ++fn) {
                const int ib = (ks * 4 + wnh + fn) * 512 + l * 8;
                bh[fn][ks] = *(const short8*)(&Bh[p][ib]);
                bl[fn][ks] = *(const short8*)(&Bl[p][ib]);
            }
        #pragma unroll
        for (int ks = 0; ks < 2; ++ks)
            #pragma unroll
            for (int fm = 0; fm < 2; ++fm)
                #pragma unroll
                for (int fn = 0; fn < 2; ++fn) {
                    acc[fm][fn] = __builtin_amdgcn_mfma_f32_32x32x16_bf16(ah[fm][ks], bh[fn][ks], acc[fm][fn], 0, 0, 0);
                    acc[fm][fn] = __builtin_amdgcn_mfma_f32_32x32x16_bf16(ah[fm][ks], bl[fn][ks], acc[fm][fn], 0, 0, 0);
                    acc[fm][fn] = __builtin_amdgcn_mfma_f32_32x32x16_bf16(al[fm][ks], bh[fn][ks], acc[fm][fn], 0, 0, 0);
                }
        __syncthreads();   // drains prefetch + protects buffer reuse
        p ^= 1;
    }
#undef STAGE

    // epilogue: D col = lane&31, row = (r&3) + 8*(r>>2) + 4*(lane>>5)
    #pragma unroll
    for (int fm = 0; fm < 2; ++fm)
        #pragma unroll
        for (int fn = 0; fn < 2; ++fn) {
            const int mb = mBase + (wmh + fm) * 32 + lh * 4;
            const int nb = nBase + (wnh + fn) * 32 + l31;
            #pragma unroll
            for (int r = 0; r < 16; ++r) {
                const int m = mb + (r & 3) + 8 * (r >> 2);
                float v = acc[fm][fn][r];
                const size_t off = (size_t)m * HW + nb;
                if (GATE) {
                    const float g = 1.f / (1.f + expf(-v));
                    v = g * q1p[off] + (1.f - g) * q2p[off];
                }
                Out[off] = v;
            }
        }
}

// ---------------------------------------------------------------------------
// Depthwise 3x3, SAME (zero) padding. Per-batch: in/out are [Cg, HW].
// ---------------------------------------------------------------------------
__global__ __launch_bounds__(256)
void dw3x3_k(const float* __restrict__ in, const float* __restrict__ w9,
             float* __restrict__ out)
{
    const int c  = blockIdx.y;
    const int y0 = blockIdx.x * 8;
    __shared__ float tile[10][IMW];

    const float* inc = in + (size_t)c * HW;
    for (int i = threadIdx.x; i < 10 * IMW; i += 256) {
        const int ry = i >> 7, rx = i & 127;
        const int gy = y0 + ry - 1;
        tile[ry][rx] = ((unsigned)gy < (unsigned)IMH) ? inc[gy * IMW + rx] : 0.f;
    }
    float w[9];
    #pragma unroll
    for (int i = 0; i < 9; ++i) w[i] = w9[c * 9 + i];
    __syncthreads();

    const int x  = threadIdx.x & 127;
    const int r0 = threadIdx.x >> 7;
    #pragma unroll
    for (int kk = 0; kk < 4; ++kk) {
        const int ry = r0 * 4 + kk;
        float s = 0.f;
        #pragma unroll
        for (int dy = 0; dy < 3; ++dy) {
            #pragma unroll
            for (int dx = 0; dx < 3; ++dx) {
                const int xx = x + dx - 1;
                const float v = ((unsigned)xx < (unsigned)IMW) ? tile[ry + dy][xx] : 0.f;
                s += w[dy * 3 + dx] * v;
            }
        }
        out[(size_t)c * HW + (y0 + ry) * IMW + x] = s;
    }
}

// ---------------------------------------------------------------------------
// Gram + sum-of-squares (unchanged, validated).
// ---------------------------------------------------------------------------
__global__ __launch_bounds__(256)
void gram_k(const float* __restrict__ q, const float* __restrict__ k,
            float* __restrict__ S, float* __restrict__ ssq, float* __restrict__ ssk)
{
    const int h = blockIdx.y;
    __shared__ float qs[48][65];
    __shared__ float ks[48][65];
    const int t   = threadIdx.x;
    const int tdd = t & 15;
    const int tcc = t >> 4;

    float acc[3][3];
    #pragma unroll
    for (int i = 0; i < 3; ++i)
        #pragma unroll
        for (int j = 0; j < 3; ++j) acc[i][j] = 0.f;
    float sq = 0.f, sk = 0.f;

    for (int ch = 0; ch < 8; ++ch) {
        const int n0 = (blockIdx.x + ch * 32) * 64;
        __syncthreads();
        for (int i = t; i < 48 * 16; i += 256) {
            const int cc = i >> 4, f4 = (i & 15) * 4;
            const float4 qv = *(const float4*)(q + (size_t)(h * 48 + cc) * HW + n0 + f4);
            const float4 kv = *(const float4*)(k + (size_t)(h * 48 + cc) * HW + n0 + f4);
            qs[cc][f4 + 0] = qv.x; qs[cc][f4 + 1] = qv.y; qs[cc][f4 + 2] = qv.z; qs[cc][f4 + 3] = qv.w;
            ks[cc][f4 + 0] = kv.x; ks[cc][f4 + 1] = kv.y; ks[cc][f4 + 2] = kv.z; ks[cc][f4 + 3] = kv.w;
        }
        __syncthreads();
        #pragma unroll 4
        for (int n = 0; n < 64; ++n) {
            float qv[3], kv[3];
            #pragma unroll
            for (int j = 0; j < 3; ++j) { qv[j] = qs[tcc + 16 * j][n]; kv[j] = ks[tdd + 16 * j][n]; }
            #pragma unroll
            for (int i = 0; i < 3; ++i)
                #pragma unroll
                for (int j = 0; j < 3; ++j)
                    acc[i][j] += qv[i] * kv[j];
        }
        if (t < 48) {
            float s = 0.f;
            #pragma unroll 8
            for (int n = 0; n < 64; ++n) s += qs[t][n] * qs[t][n];
            sq += s;
        } else if (t >= 128 && t < 176) {
            const int cc = t - 128;
            float s = 0.f;
            #pragma unroll 8
            for (int n = 0; n < 64; ++n) s += ks[cc][n] * ks[cc][n];
            sk += s;
        }
    }
    #pragma unroll
    for (int i = 0; i < 3; ++i)
        #pragma unroll
        for (int j = 0; j < 3; ++j)
            atomicAdd(&S[(size_t)(h * 48 + tcc + 16 * i) * 48 + tdd + 16 * j], acc[i][j]);
    if (t < 48)                   atomicAdd(&ssq[h * 48 + t], sq);
    else if (t >= 128 && t < 176) atomicAdd(&ssk[h * 48 + t - 128], sk);
}

// ---------------------------------------------------------------------------
// Scale + softmax (unchanged).
// ---------------------------------------------------------------------------
__global__ void softmax_k(float* __restrict__ S, const float* __restrict__ ssq,
                          const float* __restrict__ ssk, const float* __restrict__ temp)
{
    const int h  = blockIdx.x;
    const int cc = threadIdx.x;
    if (cc >= 48) return;
    const float rq = 1.f / fmaxf(sqrtf(ssq[h * 48 + cc]), 1e-12f);
    const float T  = temp[h];
    float l[48];
    float mx = -1e30f;
    #pragma unroll
    for (int d = 0; d < 48; ++d) {
        const float rk = 1.f / fmaxf(sqrtf(ssk[h * 48 + d]), 1e-12f);
        const float v  = S[(size_t)(h * 48 + cc) * 48 + d] * rq * rk * T;
        l[d] = v;
        mx = fmaxf(mx, v);
    }
    float sum = 0.f;
    #pragma unroll
    for (int d = 0; d < 48; ++d) { const float e = expf(l[d] - mx); l[d] = e; sum += e; }
    const float inv = 1.f / sum;
    #pragma unroll
    for (int d = 0; d < 48; ++d) S[(size_t)(h * 48 + cc) * 48 + d] = l[d] * inv;
}

// ---------------------------------------------------------------------------
// out[h*48+c, n] = sum_d A[h,c,d] * v[h*48+d, n] (unchanged).
// ---------------------------------------------------------------------------
__global__ __launch_bounds__(256)
void attnv_k(const float* __restrict__ A, const float* __restrict__ v,
             float* __restrict__ out)
{
    const int h  = blockIdx.y;
    const int n0 = blockIdx.x * 64;
    __shared__ float As[48][48];
    __shared__ float Vs[48][64];
    const int t = threadIdx.x;

    for (int i = t; i < 48 * 12; i += 256) {
        const int cc = i / 12, d4 = (i % 12) * 4;
        *(float4*)&As[cc][d4] = *(const float4*)(A + (size_t)(h * 48 + cc) * 48 + d4);
    }
    for (int i = t; i < 48 * 16; i += 256) {
        const int dd = i >> 4, f4 = (i & 15) * 4;
        *(float4*)&Vs[dd][f4] = *(const float4*)(v + (size_t)(h * 48 + dd) * HW + n0 + f4);
    }
    __syncthreads();

    const int n4 = (t & 15) * 4;
    const int cg = t >> 4;
    float o[3][4];
    #pragma unroll
    for (int i = 0; i < 3; ++i)
        #pragma unroll
        for (int j = 0; j < 4; ++j) o[i][j] = 0.f;

    #pragma unroll
    for (int d0 = 0; d0 < 48; d0 += 8) {
        float vr[8][4];
        #pragma unroll
        for (int di = 0; di < 8; ++di) {
            const float4 x = *(const float4*)&Vs[d0 + di][n4];
            vr[di][0] = x.x; vr[di][1] = x.y; vr[di][2] = x.z; vr[di][3] = x.w;
        }
        #pragma unroll
        for (int ci = 0; ci < 3; ++ci) {
            const int cc = cg * 3 + ci;
            const float4 a0 = *(const float4*)&As[cc][d0];
            const float4 a1 = *(const float4*)&As[cc][d0 + 4];
            const float a[8] = {a0.x, a0.y, a0.z, a0.w, a1.x, a1.y, a1.z, a1.w};
            #pragma unroll
            for (int di = 0; di < 8; ++di)
                #pragma unroll
                for (int j = 0; j < 4; ++j)
                    o[ci][j] += a[di] * vr[di][j];
        }
    }
    #pragma unroll
    for (int ci = 0; ci < 3; ++ci) {
        const int cc = cg * 3 + ci;
        *(float4*)(out + (size_t)(h * 48 + cc) * HW + n0 + n4) =
            make_float4(o[ci][0], o[ci][1], o[ci][2], o[ci][3]);
    }
}

// ---------------------------------------------------------------------------
extern "C" void kernel_launch(void* const* d_in, const int* in_sizes, int n_in,
                              void* d_out, int out_size, void* d_ws, size_t ws_size,
                              hipStream_t stream)
{
    const float* prompt    = (const float*)d_in[0];
    const float* xmod      = (const float*)d_in[1];
    const float* yin       = (const float*)d_in[2];
    const float* q1_w      = (const float*)d_in[3];
    const float* q2_w      = (const float*)d_in[4];
    const float* q_dw_w    = (const float*)d_in[5];
    const float* gate_dw_w = (const float*)d_in[6];
    const float* gate_pw_w = (const float*)d_in[7];
    const float* kv_w      = (const float*)d_in[8];
    const float* kv_dw_w   = (const float*)d_in[9];
    const float* proj_w    = (const float*)d_in[10];
    const float* temp      = (const float*)d_in[11];
    float* out = (float*)d_out;
    float* ws  = (float*)d_ws;

    const size_t BUF  = (size_t)CC2 * HW;          // 12.58M floats
    const size_t HALF = (size_t)CC * HW;
    float* q12 = ws;                               // [768,HW]: q1|q2 -> qin|q
    float* t1  = ws + BUF;                         // [768,HW]: dcat -> k|v  (+XT384 alias)
    float* t2  = ws + 2 * BUF;                     // [768,HW]: XT768 -> kvp -> attn_out
    u16*   Wh  = (u16*)(ws + 3 * BUF);             // 1032192 u16
    u16*   Wl  = Wh + 1032192;
    float* S   = ws + 3 * BUF + 1032192;           // [8,48,48]
    float* ssq = S + NH * DH * DH;
    float* ssk = ssq + CC;

    // packed weight offsets in Wh/Wl (u16 elems)
    const int WO_Q1 = 0, WO_Q2 = 147456, WO_GATE = 294912, WO_KV = 589824, WO_PROJ = 884736;

    // XT aliases
    u16* XT2h = (u16*)t2;                // K=768 capacity
    u16* XT2l = XT2h + (size_t)HW * CC2;
    u16* XT1h = (u16*)t1;                // K=384 capacity
    u16* XT1l = XT1h + (size_t)HW * CC;

    const dim3 blk(256);

    // one-time weight split+pack
    wsplit_k<<<dim3(504), blk, 0, stream>>>(q1_w, q2_w, gate_pw_w, kv_w, proj_w, Wh, Wl);

    for (int b = 0; b < 2; ++b) {
        const size_t ib = (size_t)b * CC * HW;

        // q1 = q1_w * prompt -> q12[0:384]
        trsplit_k<<<dim3(256, 6), blk, 0, stream>>>(prompt + ib, XT1h, XT1l, CC);
        gemm_mfma_k<0><<<dim3(128, 3), blk, 0, stream>>>(Wh + WO_Q1, Wl + WO_Q1, XT1h, XT1l, CC, q12, nullptr, nullptr);
        // q2 = q2_w * x_mod -> q12[384:768]
        trsplit_k<<<dim3(256, 6), blk, 0, stream>>>(xmod + ib, XT1h, XT1l, CC);
        gemm_mfma_k<0><<<dim3(128, 3), blk, 0, stream>>>(Wh + WO_Q2, Wl + WO_Q2, XT1h, XT1l, CC, q12 + HALF, nullptr, nullptr);
        // dcat = dw3x3(q12, gate_dw_w) -> t1 (768 ch)
        dw3x3_k<<<dim3(16, CC2), blk, 0, stream>>>(q12, gate_dw_w, t1);
        // gate pw + sigmoid + blend -> q12[0:384] (in place over q1)
        trsplit_k<<<dim3(256, 12), blk, 0, stream>>>(t1, XT2h, XT2l, CC2);
        gemm_mfma_k<1><<<dim3(128, 3), blk, 0, stream>>>(Wh + WO_GATE, Wl + WO_GATE, XT2h, XT2l, CC2, q12, q12, q12 + HALF);
        // q = dw3x3(qin, q_dw_w) -> q12[384:768]
        dw3x3_k<<<dim3(16, CC), blk, 0, stream>>>(q12, q_dw_w, q12 + HALF);
        // kvp = kv_w * y -> t2
        trsplit_k<<<dim3(256, 6), blk, 0, stream>>>(yin + ib, XT1h, XT1l, CC);
        gemm_mfma_k<0><<<dim3(128, 6), blk, 0, stream>>>(Wh + WO_KV, Wl + WO_KV, XT1h, XT1l, CC, t2, nullptr, nullptr);
        // kv = dw3x3(t2, kv_dw_w) -> t1 : k|v
        dw3x3_k<<<dim3(16, CC2), blk, 0, stream>>>(t2, kv_dw_w, t1);
        // Gram + sumsq
        hipMemsetAsync(S, 0, (NH * DH * DH + 2 * CC) * sizeof(float), stream);
        gram_k<<<dim3(32, NH), blk, 0, stream>>>(q12 + HALF, t1, S, ssq, ssk);
        softmax_k<<<dim3(NH), dim3(64), 0, stream>>>(S, ssq, ssk, temp);
        // attn_out = A * v -> t2[0:384]
        attnv_k<<<dim3(HW / 64, NH), blk, 0, stream>>>(S, t1 + HALF, t2);
        // final projection -> out
        trsplit_k<<<dim3(256, 6), blk, 0, stream>>>(t2, XT1h, XT1l, CC);
        gemm_mfma_k<0><<<dim3(128, 3), blk, 0, stream>>>(Wh + WO_PROJ, Wl + WO_PROJ, XT1h, XT1l, CC, out + ib, nullptr, nullptr);
    }
}